// Round 7
// baseline (81.742 us; speedup 1.0000x reference)
//
#include <hip/hip_runtime.h>
#include <math.h>

#define B 4
#define TQ 512
#define TV 1024
#define DQ 256
#define DV 256
#define UNITS 64
#define NQROW (B * TQ)   // 2048
#define NKROW (B * TV)   // 4096

#define CEXP  2.885390081777927f    // 2*log2(e): exp(2x) == exp2(CEXP*x)
#define LOG2E 1.4426950408889634f

__device__ __forceinline__ float fast_exp2(float x) {
#if __has_builtin(__builtin_amdgcn_exp2f)
    return __builtin_amdgcn_exp2f(x);
#else
    return __expf(0.6931471805599453f * x);
#endif
}

__device__ __forceinline__ float wave_max(float v) {
    #pragma unroll
    for (int off = 32; off > 0; off >>= 1)
        v = fmaxf(v, __shfl_xor(v, off, 64));
    return v;
}
__device__ __forceinline__ float wave_sum(float v) {
    #pragma unroll
    for (int off = 32; off > 0; off >>= 1)
        v += __shfl_xor(v, off, 64);
    return v;
}

// ---- prepack: wT[u][d] = w[d][u]; 8 blocks x 64 thr, register transpose ----
__global__ __launch_bounds__(64) void prepack_kernel(
        const float* __restrict__ w1, const float* __restrict__ w2,
        float* __restrict__ wT1, float* __restrict__ wT2) {
    const int u = threadIdx.x;             // 0..63
    const int blk = blockIdx.x;            // 0..7
    const float* w = (blk < 4) ? w1 : w2;
    float* wT      = (blk < 4) ? wT1 : wT2;
    const int d0 = (blk & 3) * 64;
    float v[64];
    #pragma unroll
    for (int i = 0; i < 64; ++i)           // coalesced 256B loads
        v[i] = w[(size_t)(d0 + i) * UNITS + u];
    float* dst = wT + (size_t)u * DQ + d0;
    #pragma unroll
    for (int i = 0; i < 16; ++i) {
        float4 t; t.x = v[4*i]; t.y = v[4*i+1]; t.z = v[4*i+2]; t.w = v[4*i+3];
        *(float4*)(dst + 4 * i) = t;
    }
}

// ---- projections: 2 rows/wave, 8 rows/block, rows via LDS, wT float4 loads --
#define RPB 8
__global__ __launch_bounds__(256) void proj_kernel(
        const float* __restrict__ query, const float* __restrict__ value,
        const float* __restrict__ wT1, const float* __restrict__ wT2,
        float* __restrict__ Eq, float* __restrict__ EkT) {
    __shared__ float rows[RPB][DQ];        // 8 KB
    __shared__ float lt[64][RPB + 4];      // k transpose bounce (padded)
    const int tid = threadIdx.x;
    const int u   = tid & 63;
    const int wid = tid >> 6;
    const int row0 = blockIdx.x * RPB;
    const bool isq = row0 < NQROW;
    const float* in = isq ? query + (size_t)row0 * DQ
                          : value + (size_t)(row0 - NQROW) * DQ;
    const float* wT = isq ? wT1 : wT2;

    {   // stage 8 rows coalesced
        const float4* src = (const float4*)in;
        float4* dst = (float4*)&rows[0][0];
        dst[tid]       = src[tid];
        dst[tid + 256] = src[tid + 256];
    }
    __syncthreads();

    const int r0 = wid * 2;
    const float4* wrow = (const float4*)(wT + (size_t)u * DQ);
    float a0 = 0.f, a1 = 0.f, b0 = 0.f, b1 = 0.f;
    #pragma unroll 8
    for (int c = 0; c < DQ / 4; ++c) {
        const float4 wv = wrow[c];
        const float4 t0 = *(const float4*)&rows[r0][4 * c];
        const float4 t1 = *(const float4*)&rows[r0 + 1][4 * c];
        a0 = fmaf(t0.x, wv.x, a0); a1 = fmaf(t0.y, wv.y, a1);
        a0 = fmaf(t0.z, wv.z, a0); a1 = fmaf(t0.w, wv.w, a1);
        b0 = fmaf(t1.x, wv.x, b0); b1 = fmaf(t1.y, wv.y, b1);
        b0 = fmaf(t1.z, wv.z, b0); b1 = fmaf(t1.w, wv.w, b1);
    }
    const float ea = fast_exp2(CEXP * (a0 + a1));
    const float eb = fast_exp2(CEXP * (b0 + b1));

    if (isq) {
        Eq[(size_t)(row0 + r0) * UNITS + u]     = ea;
        Eq[(size_t)(row0 + r0 + 1) * UNITS + u] = eb;
    } else {
        lt[u][r0]     = ea;
        lt[u][r0 + 1] = eb;
    }
    __syncthreads();
    if (!isq) {
        const int uu = tid >> 2, p = tid & 3;
        const int col0 = row0 - NQROW;
        float2 v2;
        v2.x = lt[uu][2 * p];
        v2.y = lt[uu][2 * p + 1];
        *(float2*)(EkT + (size_t)uu * NKROW + col0 + 2 * p) = v2;
    }
}

// ---- scores + softmax: u-quad rcp fusion, coalesced EkT (lane = v) ----
#define QB 4
#define SNT 512
#define SNW (SNT / 64)
// grid = NQROW/QB = 512 blocks, 512 threads; thread owns v = {2*tid, 2*tid+1}
__global__ __launch_bounds__(SNT) void score_kernel(
        const float* __restrict__ Eq,      // [NQROW][UNITS]
        const float* __restrict__ EkT,     // [UNITS][NKROW]
        const float* __restrict__ scale,   // [UNITS]
        float* __restrict__ out_attn) {    // [NQROW][TV]
    __shared__ float q_lds[QB][UNITS];
    __shared__ float s_lds[UNITS];
    __shared__ float redm[QB][SNW];
    __shared__ float reds[QB][SNW];

    const int tid = threadIdx.x, lane = tid & 63, wid = tid >> 6;
    int bid = blockIdx.x;
    bid = (bid & 7) * ((NQROW / QB) >> 3) + (bid >> 3);   // XCD swizzle, bijective
    const int b  = bid / (TQ / QB);
    const int q0 = (bid % (TQ / QB)) * QB;

    if (tid < QB * UNITS)
        q_lds[tid >> 6][tid & 63] =
            Eq[(size_t)(b * TQ + q0 + (tid >> 6)) * UNITS + (tid & 63)];
    else if (tid < QB * UNITS + UNITS)
        s_lds[tid - QB * UNITS] = scale[tid - QB * UNITS];
    __syncthreads();

    const float* ekc = EkT + (size_t)b * TV + 2 * tid;
    float acc0[QB] = {}, acc1[QB] = {};

    #pragma unroll 4
    for (int u4 = 0; u4 < UNITS / 4; ++u4) {
        const float2 ek0 = *(const float2*)(ekc + (size_t)(4 * u4 + 0) * NKROW);
        const float2 ek1 = *(const float2*)(ekc + (size_t)(4 * u4 + 1) * NKROW);
        const float2 ek2 = *(const float2*)(ekc + (size_t)(4 * u4 + 2) * NKROW);
        const float2 ek3 = *(const float2*)(ekc + (size_t)(4 * u4 + 3) * NKROW);
        const float4 s4 = *(const float4*)(s_lds + 4 * u4);
        #pragma unroll
        for (int q = 0; q < QB; ++q) {
            const float4 eq = *(const float4*)(&q_lds[q][4 * u4]);
            // v0: sum_{i=0..3} s_i / t_i  with one rcp
            {
                float t0 = fmaf(eq.x, ek0.x, 1.f);
                float t1 = fmaf(eq.y, ek1.x, 1.f);
                float t2 = fmaf(eq.z, ek2.x, 1.f);
                float t3 = fmaf(eq.w, ek3.x, 1.f);
                float p01 = t0 * t1, p23 = t2 * t3;
                float A  = fmaf(s4.y, t0, s4.x * t1);
                float Bq = fmaf(s4.w, t2, s4.z * t3);
                float num = fmaf(Bq, p01, A * p23);
                float r = __builtin_amdgcn_rcpf(p01 * p23);
                acc0[q] = fmaf(num, r, acc0[q]);
            }
            // v1
            {
                float t0 = fmaf(eq.x, ek0.y, 1.f);
                float t1 = fmaf(eq.y, ek1.y, 1.f);
                float t2 = fmaf(eq.z, ek2.y, 1.f);
                float t3 = fmaf(eq.w, ek3.y, 1.f);
                float p01 = t0 * t1, p23 = t2 * t3;
                float A  = fmaf(s4.y, t0, s4.x * t1);
                float Bq = fmaf(s4.w, t2, s4.z * t3);
                float num = fmaf(Bq, p01, A * p23);
                float r = __builtin_amdgcn_rcpf(p01 * p23);
                acc1[q] = fmaf(num, r, acc1[q]);
            }
        }
    }

    // scores (shift-invariant): x = -2 * acc
    float x0[QB], x1[QB], m[QB];
    #pragma unroll
    for (int q = 0; q < QB; ++q) {
        x0[q] = -2.f * acc0[q];
        x1[q] = -2.f * acc1[q];
        m[q] = wave_max(fmaxf(x0[q], x1[q]));
        if (lane == 0) redm[q][wid] = m[q];
    }
    __syncthreads();
    #pragma unroll
    for (int q = 0; q < QB; ++q) {
        float mm = redm[q][0];
        #pragma unroll
        for (int i = 1; i < SNW; ++i) mm = fmaxf(mm, redm[q][i]);
        m[q] = mm;
    }
    float e0[QB], e1[QB];
    #pragma unroll
    for (int q = 0; q < QB; ++q) {
        const float mm = m[q] * LOG2E;
        e0[q] = fast_exp2(fmaf(x0[q], LOG2E, -mm));
        e1[q] = fast_exp2(fmaf(x1[q], LOG2E, -mm));
        float s = wave_sum(e0[q] + e1[q]);
        if (lane == 0) reds[q][wid] = s;
    }
    __syncthreads();
    #pragma unroll
    for (int q = 0; q < QB; ++q) {
        float ss = reds[q][0];
        #pragma unroll
        for (int i = 1; i < SNW; ++i) ss += reds[q][i];
        const float inv = __builtin_amdgcn_rcpf(ss);
        float2 o; o.x = e0[q] * inv; o.y = e1[q] * inv;
        float* arow = out_attn + (size_t)(b * TQ + q0 + q) * TV;
        *(float2*)(arow + 2 * tid) = o;
    }
}

// ---- context partial: QC q-rows x TV/SPLIT v-range per block ----
template <int QC, int SPLIT>
__global__ __launch_bounds__(512) void ctx_kernel(
        const float* __restrict__ attn,    // [NQROW][TV]
        const float* __restrict__ value,   // [B][TV][DV]
        float* __restrict__ dst) {         // [SPLIT][NQROW][DV]
    constexpr int TVC = TV / SPLIT;
    constexpr int QT  = QC / 2;            // q rows per thread (512 thr / 256 d)
    const int tid = threadIdx.x;
    constexpr int G = (NQROW / QC) * SPLIT;
    int bid = blockIdx.x;
    bid = (bid & 7) * (G >> 3) + (bid >> 3);   // XCD swizzle (G % 8 == 0)
    const int qc = bid / SPLIT, vs = bid % SPLIT;
    const int b  = qc / (TQ / QC);
    const int q0 = (qc % (TQ / QC)) * QC;
    const int v0 = vs * TVC;
    const int d  = tid & (DV - 1);
    const int qh = __builtin_amdgcn_readfirstlane(tid >> 8) * QT;

    const float* ab = attn + (size_t)(b * TQ + q0 + qh) * TV + v0;
    const float* vb = value + ((size_t)b * TV + v0) * DV + d;

    float acc[QT] = {};
    #pragma unroll 2
    for (int v4 = 0; v4 < TVC / 4; ++v4) {
        float4 aq[QT];
        #pragma unroll
        for (int j = 0; j < QT; ++j)
            aq[j] = *(const float4*)(ab + (size_t)j * TV + v4 * 4);
        #pragma unroll
        for (int k = 0; k < 4; ++k) {
            float val = vb[(size_t)(v4 * 4 + k) * DV];
            #pragma unroll
            for (int j = 0; j < QT; ++j)
                acc[j] = fmaf(((const float*)&aq[j])[k], val, acc[j]);
        }
    }
    float* o = dst + (size_t)vs * (NQROW * DV) + (size_t)(b * TQ + q0 + qh) * DV + d;
    #pragma unroll
    for (int j = 0; j < QT; ++j)
        o[(size_t)j * DV] = acc[j];
}

// out[i] = sum over 4 partials
__global__ __launch_bounds__(256) void reduce_kernel(
        const float* __restrict__ part, float* __restrict__ out) {
    constexpr size_t S = (size_t)NQROW * DV / 4;   // float4 count per partial
    const size_t i = (size_t)blockIdx.x * 256 + threadIdx.x;
    const float4* p = (const float4*)part;
    float4 a = p[i], b4 = p[i + S], c = p[i + 2 * S], d4 = p[i + 3 * S];
    float4 r;
    r.x = (a.x + b4.x) + (c.x + d4.x);
    r.y = (a.y + b4.y) + (c.y + d4.y);
    r.z = (a.z + b4.z) + (c.z + d4.z);
    r.w = (a.w + b4.w) + (c.w + d4.w);
    ((float4*)out)[i] = r;
}

extern "C" void kernel_launch(void* const* d_in, const int* in_sizes, int n_in,
                              void* d_out, int out_size, void* d_ws, size_t ws_size,
                              hipStream_t stream) {
    const float* query = (const float*)d_in[0];
    const float* value = (const float*)d_in[1];
    const float* w1    = (const float*)d_in[2];
    const float* w2    = (const float*)d_in[3];
    const float* scale = (const float*)d_in[4];

    float* out      = (float*)d_out;
    float* out_ctx  = out;                         // [NQROW*DV]
    float* out_attn = out + (size_t)NQROW * DV;    // [NQROW*TV]

    float* Eq   = (float*)d_ws;                    // NQROW*UNITS
    float* EkT  = Eq + (size_t)NQROW * UNITS;      // UNITS*NKROW
    float* wT1  = EkT + (size_t)UNITS * NKROW;     // UNITS*DQ
    float* wT2  = wT1 + (size_t)UNITS * DQ;        // UNITS*DV
    float* part = wT2 + (size_t)UNITS * DV;        // 4 * NQROW*DV

    const size_t need = ((size_t)NQROW * UNITS + (size_t)UNITS * NKROW +
                         (size_t)2 * UNITS * DQ + (size_t)4 * NQROW * DV) * sizeof(float);

    prepack_kernel<<<dim3(8), 64, 0, stream>>>(w1, w2, wT1, wT2);
    proj_kernel<<<dim3((NQROW + NKROW) / RPB), 256, 0, stream>>>(
        query, value, wT1, wT2, Eq, EkT);
    score_kernel<<<dim3(NQROW / QB), SNT, 0, stream>>>(Eq, EkT, scale, out_attn);
    if (ws_size >= need) {
        ctx_kernel<16, 4><<<dim3((NQROW / 16) * 4), 512, 0, stream>>>(out_attn, value, part);
        reduce_kernel<<<dim3(NQROW * DV / 4 / 256), 256, 0, stream>>>(part, out_ctx);
    } else {
        ctx_kernel<8, 1><<<dim3(NQROW / 8), 512, 0, stream>>>(out_attn, value, out_ctx);
    }
}

// Round 8
// 64.701 us; speedup vs baseline: 1.2634x; 1.2634x over previous
//
#include <hip/hip_runtime.h>
#include <math.h>

#define B 4
#define TQ 512
#define TV 1024
#define DQ 256
#define DV 256
#define UNITS 64
#define NQROW (B * TQ)   // 2048
#define NKROW (B * TV)   // 4096

#define CEXP  2.885390081777927f    // 2*log2(e): exp(2x) == exp2(CEXP*x)
#define LOG2E 1.4426950408889634f

__device__ __forceinline__ float fast_exp2(float x) {
#if __has_builtin(__builtin_amdgcn_exp2f)
    return __builtin_amdgcn_exp2f(x);
#else
    return __expf(0.6931471805599453f * x);
#endif
}

__device__ __forceinline__ float wave_max(float v) {
    #pragma unroll
    for (int off = 32; off > 0; off >>= 1)
        v = fmaxf(v, __shfl_xor(v, off, 64));
    return v;
}
__device__ __forceinline__ float wave_sum(float v) {
    #pragma unroll
    for (int off = 32; off > 0; off >>= 1)
        v += __shfl_xor(v, off, 64);
    return v;
}

// ---- projections: 1 row/wave, 8 waves/block (6 waves/SIMD), LDS row stage --
// Blocks 0..255: query rows -> Eq row-major [NQROW][UNITS].
// Blocks 256..767: value rows -> EkT transposed [UNITS][NKROW] via LDS bounce.
// w loads stay scalar+coalesced (lane = u -> consecutive addresses).
#define RPB 8
__global__ __launch_bounds__(512) void proj_kernel(
        const float* __restrict__ query, const float* __restrict__ value,
        const float* __restrict__ w1, const float* __restrict__ w2,
        float* __restrict__ Eq, float* __restrict__ EkT) {
    __shared__ float rows[RPB][DQ];        // 8 KB
    __shared__ float lt[64][RPB + 4];      // k transpose bounce (padded)
    const int tid = threadIdx.x;
    const int u   = tid & 63;
    const int wid = tid >> 6;              // 0..7 -> this wave's row
    const int row0 = blockIdx.x * RPB;
    const bool isq = row0 < NQROW;
    const float* in = isq ? query + (size_t)row0 * DQ
                          : value + (size_t)(row0 - NQROW) * DQ;
    const float* w  = isq ? w1 : w2;

    // stage 8 rows (2048 floats) with one coalesced float4 per thread
    ((float4*)&rows[0][0])[tid] = ((const float4*)in)[tid];
    __syncthreads();

    float a0 = 0.f, a1 = 0.f;
    #pragma unroll 8
    for (int c = 0; c < DQ / 4; ++c) {
        const float w0v = w[(4 * c + 0) * UNITS + u];
        const float w1v = w[(4 * c + 1) * UNITS + u];
        const float w2v = w[(4 * c + 2) * UNITS + u];
        const float w3v = w[(4 * c + 3) * UNITS + u];
        const float4 t = *(const float4*)&rows[wid][4 * c];   // broadcast read
        a0 = fmaf(t.x, w0v, a0); a1 = fmaf(t.y, w1v, a1);
        a0 = fmaf(t.z, w2v, a0); a1 = fmaf(t.w, w3v, a1);
    }
    const float e = fast_exp2(CEXP * (a0 + a1));

    if (isq) {
        Eq[(size_t)(row0 + wid) * UNITS + u] = e;
    } else {
        lt[u][wid] = e;
    }
    __syncthreads();
    if (!isq) {
        // write EkT[u][col0..col0+7]: 512 floats, 512 threads -> 1 each
        const int uu = tid >> 3, p = tid & 7;
        EkT[(size_t)uu * NKROW + (row0 - NQROW) + p] = lt[uu][p];
    }
}

// ---- scores + softmax: coalesced EkT loads (lane = v), QB q-rows per block --
#define QB 4
#define SNT 512
#define SNW (SNT / 64)
// grid = NQROW/QB = 512 blocks, 512 threads; thread owns v = {2*tid, 2*tid+1}
__global__ __launch_bounds__(SNT) void score_kernel(
        const float* __restrict__ Eq,      // [NQROW][UNITS]
        const float* __restrict__ EkT,     // [UNITS][NKROW]
        const float* __restrict__ scale,   // [UNITS]
        float* __restrict__ out_attn) {    // [NQROW][TV]
    __shared__ float q_lds[QB][UNITS];
    __shared__ float s_lds[UNITS];
    __shared__ float redm[QB][SNW];
    __shared__ float reds[QB][SNW];

    const int tid = threadIdx.x, lane = tid & 63, wid = tid >> 6;
    int bid = blockIdx.x;
    bid = (bid & 7) * ((NQROW / QB) >> 3) + (bid >> 3);   // XCD swizzle, bijective
    const int b  = bid / (TQ / QB);
    const int q0 = (bid % (TQ / QB)) * QB;

    if (tid < QB * UNITS)
        q_lds[tid >> 6][tid & 63] =
            Eq[(size_t)(b * TQ + q0 + (tid >> 6)) * UNITS + (tid & 63)];
    else if (tid < QB * UNITS + UNITS)
        s_lds[tid - QB * UNITS] = scale[tid - QB * UNITS];
    __syncthreads();

    const float* ekc = EkT + (size_t)b * TV + 2 * tid;
    float2 acc[QB];
    #pragma unroll
    for (int q = 0; q < QB; ++q) { acc[q].x = 0.f; acc[q].y = 0.f; }

    #pragma unroll 8
    for (int u = 0; u < UNITS; ++u) {
        float2 ek = *(const float2*)(ekc + (size_t)u * NKROW);
        const float s = s_lds[u];
        #pragma unroll
        for (int q = 0; q < QB; ++q) {
            const float eq = q_lds[q][u];
            float t0 = fmaf(eq, ek.x, 1.f);
            float t1 = fmaf(eq, ek.y, 1.f);
            acc[q].x = fmaf(s, __builtin_amdgcn_rcpf(t0), acc[q].x);
            acc[q].y = fmaf(s, __builtin_amdgcn_rcpf(t1), acc[q].y);
        }
    }

    // scores (shift-invariant): x = -2 * acc
    float x0[QB], x1[QB], m[QB];
    #pragma unroll
    for (int q = 0; q < QB; ++q) {
        x0[q] = -2.f * acc[q].x;
        x1[q] = -2.f * acc[q].y;
        m[q] = wave_max(fmaxf(x0[q], x1[q]));
        if (lane == 0) redm[q][wid] = m[q];
    }
    __syncthreads();
    #pragma unroll
    for (int q = 0; q < QB; ++q) {
        float mm = redm[q][0];
        #pragma unroll
        for (int i = 1; i < SNW; ++i) mm = fmaxf(mm, redm[q][i]);
        m[q] = mm;
    }
    float e0[QB], e1[QB];
    #pragma unroll
    for (int q = 0; q < QB; ++q) {
        const float mm = m[q] * LOG2E;
        e0[q] = fast_exp2(fmaf(x0[q], LOG2E, -mm));
        e1[q] = fast_exp2(fmaf(x1[q], LOG2E, -mm));
        float s = wave_sum(e0[q] + e1[q]);
        if (lane == 0) reds[q][wid] = s;
    }
    __syncthreads();
    #pragma unroll
    for (int q = 0; q < QB; ++q) {
        float ss = reds[q][0];
        #pragma unroll
        for (int i = 1; i < SNW; ++i) ss += reds[q][i];
        const float inv = __builtin_amdgcn_rcpf(ss);
        float2 o; o.x = e0[q] * inv; o.y = e1[q] * inv;
        float* arow = out_attn + (size_t)(b * TQ + q0 + q) * TV;
        *(float2*)(arow + 2 * tid) = o;
    }
}

// ---- context partial: QC q-rows x TV/SPLIT v-range per block ----
template <int QC, int SPLIT>
__global__ __launch_bounds__(512) void ctx_kernel(
        const float* __restrict__ attn,    // [NQROW][TV]
        const float* __restrict__ value,   // [B][TV][DV]
        float* __restrict__ dst) {         // [SPLIT][NQROW][DV]
    constexpr int TVC = TV / SPLIT;
    constexpr int QT  = QC / 2;            // q rows per thread (512 thr / 256 d)
    const int tid = threadIdx.x;
    constexpr int G = (NQROW / QC) * SPLIT;
    int bid = blockIdx.x;
    bid = (bid & 7) * (G >> 3) + (bid >> 3);   // XCD swizzle (G % 8 == 0)
    const int qc = bid / SPLIT, vs = bid % SPLIT;
    const int b  = qc / (TQ / QC);
    const int q0 = (qc % (TQ / QC)) * QC;
    const int v0 = vs * TVC;
    const int d  = tid & (DV - 1);
    const int qh = __builtin_amdgcn_readfirstlane(tid >> 8) * QT;

    const float* ab = attn + (size_t)(b * TQ + q0 + qh) * TV + v0;
    const float* vb = value + ((size_t)b * TV + v0) * DV + d;

    float acc[QT] = {};
    #pragma unroll 2
    for (int v4 = 0; v4 < TVC / 4; ++v4) {
        float4 aq[QT];
        #pragma unroll
        for (int j = 0; j < QT; ++j)
            aq[j] = *(const float4*)(ab + (size_t)j * TV + v4 * 4);
        #pragma unroll
        for (int k = 0; k < 4; ++k) {
            float val = vb[(size_t)(v4 * 4 + k) * DV];
            #pragma unroll
            for (int j = 0; j < QT; ++j)
                acc[j] = fmaf(((const float*)&aq[j])[k], val, acc[j]);
        }
    }
    float* o = dst + (size_t)vs * (NQROW * DV) + (size_t)(b * TQ + q0 + qh) * DV + d;
    #pragma unroll
    for (int j = 0; j < QT; ++j)
        o[(size_t)j * DV] = acc[j];
}

// out[i] = sum over 4 partials
__global__ __launch_bounds__(256) void reduce_kernel(
        const float* __restrict__ part, float* __restrict__ out) {
    constexpr size_t S = (size_t)NQROW * DV / 4;   // float4 count per partial
    const size_t i = (size_t)blockIdx.x * 256 + threadIdx.x;
    const float4* p = (const float4*)part;
    float4 a = p[i], b4 = p[i + S], c = p[i + 2 * S], d4 = p[i + 3 * S];
    float4 r;
    r.x = (a.x + b4.x) + (c.x + d4.x);
    r.y = (a.y + b4.y) + (c.y + d4.y);
    r.z = (a.z + b4.z) + (c.z + d4.z);
    r.w = (a.w + b4.w) + (c.w + d4.w);
    ((float4*)out)[i] = r;
}

extern "C" void kernel_launch(void* const* d_in, const int* in_sizes, int n_in,
                              void* d_out, int out_size, void* d_ws, size_t ws_size,
                              hipStream_t stream) {
    const float* query = (const float*)d_in[0];
    const float* value = (const float*)d_in[1];
    const float* w1    = (const float*)d_in[2];
    const float* w2    = (const float*)d_in[3];
    const float* scale = (const float*)d_in[4];

    float* out      = (float*)d_out;
    float* out_ctx  = out;                         // [NQROW*DV]
    float* out_attn = out + (size_t)NQROW * DV;    // [NQROW*TV]

    float* Eq   = (float*)d_ws;                    // NQROW*UNITS
    float* EkT  = Eq + (size_t)NQROW * UNITS;      // UNITS*NKROW
    float* part = EkT + (size_t)UNITS * NKROW;     // 4 * NQROW*DV

    const size_t need = ((size_t)NQROW * UNITS + (size_t)UNITS * NKROW +
                         (size_t)4 * NQROW * DV) * sizeof(float);

    proj_kernel<<<dim3((NQROW + NKROW) / RPB), 512, 0, stream>>>(
        query, value, w1, w2, Eq, EkT);
    score_kernel<<<dim3(NQROW / QB), SNT, 0, stream>>>(Eq, EkT, scale, out_attn);
    if (ws_size >= need) {
        ctx_kernel<16, 4><<<dim3((NQROW / 16) * 4), 512, 0, stream>>>(out_attn, value, part);
        reduce_kernel<<<dim3(NQROW * DV / 4 / 256), 256, 0, stream>>>(part, out_ctx);
    } else {
        ctx_kernel<8, 1><<<dim3(NQROW / 8), 512, 0, stream>>>(out_attn, value, out_ctx);
    }
}

// Round 9
// 59.564 us; speedup vs baseline: 1.3723x; 1.0862x over previous
//
#include <hip/hip_runtime.h>
#include <math.h>

#define B 4
#define TQ 512
#define TV 1024
#define DQ 256
#define DV 256
#define UNITS 64
#define NQROW (B * TQ)   // 2048
#define NKROW (B * TV)   // 4096

#define CEXP  2.885390081777927f    // 2*log2(e): exp(2x) == exp2(CEXP*x)
#define LOG2E 1.4426950408889634f

__device__ __forceinline__ float fast_exp2(float x) {
#if __has_builtin(__builtin_amdgcn_exp2f)
    return __builtin_amdgcn_exp2f(x);
#else
    return __expf(0.6931471805599453f * x);
#endif
}

__device__ __forceinline__ float wave_sum(float v) {
    #pragma unroll
    for (int off = 32; off > 0; off >>= 1)
        v += __shfl_xor(v, off, 64);
    return v;
}

// ---- projections: 2 rows/wave, 8 rows/block, rows staged via LDS ----
// (round-6 known-good: 60.1 us config — unchanged)
#define RPB 8
__global__ __launch_bounds__(256) void proj_kernel(
        const float* __restrict__ query, const float* __restrict__ value,
        const float* __restrict__ w1, const float* __restrict__ w2,
        float* __restrict__ Eq, float* __restrict__ EkT) {
    __shared__ float rows[RPB][DQ];        // 8 KB
    __shared__ float lt[64][RPB + 4];      // k transpose bounce (padded)
    const int tid = threadIdx.x;
    const int u   = tid & 63;
    const int wid = tid >> 6;
    const int row0 = blockIdx.x * RPB;
    const bool isq = row0 < NQROW;
    const float* in = isq ? query + (size_t)row0 * DQ
                          : value + (size_t)(row0 - NQROW) * DQ;
    const float* w  = isq ? w1 : w2;

    {   // stage 8 rows (2048 floats) coalesced
        const float4* src = (const float4*)in;
        float4* dst = (float4*)&rows[0][0];
        dst[tid]       = src[tid];
        dst[tid + 256] = src[tid + 256];
    }
    __syncthreads();

    const int r0 = wid * 2;
    float a0 = 0.f, a1 = 0.f, b0 = 0.f, b1 = 0.f;
    #pragma unroll 8
    for (int c = 0; c < DQ / 4; ++c) {
        const float w0v = w[(4 * c + 0) * UNITS + u];
        const float w1v = w[(4 * c + 1) * UNITS + u];
        const float w2v = w[(4 * c + 2) * UNITS + u];
        const float w3v = w[(4 * c + 3) * UNITS + u];
        const float4 t0 = *(const float4*)&rows[r0][4 * c];
        const float4 t1 = *(const float4*)&rows[r0 + 1][4 * c];
        a0 = fmaf(t0.x, w0v, a0); a1 = fmaf(t0.y, w1v, a1);
        a0 = fmaf(t0.z, w2v, a0); a1 = fmaf(t0.w, w3v, a1);
        b0 = fmaf(t1.x, w0v, b0); b1 = fmaf(t1.y, w1v, b1);
        b0 = fmaf(t1.z, w2v, b0); b1 = fmaf(t1.w, w3v, b1);
    }
    const float ea = fast_exp2(CEXP * (a0 + a1));
    const float eb = fast_exp2(CEXP * (b0 + b1));

    if (isq) {
        Eq[(size_t)(row0 + r0) * UNITS + u]     = ea;
        Eq[(size_t)(row0 + r0 + 1) * UNITS + u] = eb;
    } else {
        lt[u][r0]     = ea;
        lt[u][r0 + 1] = eb;
    }
    __syncthreads();
    if (!isq) {
        const int uu = tid >> 2, p = tid & 3;
        const int col0 = row0 - NQROW;
        float2 v2;
        v2.x = lt[uu][2 * p];
        v2.y = lt[uu][2 * p + 1];
        *(float2*)(EkT + (size_t)uu * NKROW + col0 + 2 * p) = v2;
    }
}

// ---- scores + softmax: u-quad rcp fusion + no-max softmax ----
// |score| <= 2*max(sum s+, sum |s-|) ~= 55 worst-case -> exp safe in fp32.
#define QB 4
#define SNT 512
#define SNW (SNT / 64)
// grid = NQROW/QB = 512 blocks, 512 threads; thread owns v = {2*tid, 2*tid+1}
__global__ __launch_bounds__(SNT) void score_kernel(
        const float* __restrict__ Eq,      // [NQROW][UNITS]
        const float* __restrict__ EkT,     // [UNITS][NKROW]
        const float* __restrict__ scale,   // [UNITS]
        float* __restrict__ out_attn) {    // [NQROW][TV]
    __shared__ float q_lds[QB][UNITS];
    __shared__ float s_lds[UNITS];
    __shared__ float reds[QB][SNW];

    const int tid = threadIdx.x, lane = tid & 63, wid = tid >> 6;
    int bid = blockIdx.x;
    bid = (bid & 7) * ((NQROW / QB) >> 3) + (bid >> 3);   // XCD swizzle, bijective
    const int b  = bid / (TQ / QB);
    const int q0 = (bid % (TQ / QB)) * QB;

    if (tid < QB * UNITS)
        q_lds[tid >> 6][tid & 63] =
            Eq[(size_t)(b * TQ + q0 + (tid >> 6)) * UNITS + (tid & 63)];
    else if (tid < QB * UNITS + UNITS)
        s_lds[tid - QB * UNITS] = scale[tid - QB * UNITS];
    __syncthreads();

    const float* ekc = EkT + (size_t)b * TV + 2 * tid;
    float acc0[QB] = {}, acc1[QB] = {};

    #pragma unroll 4
    for (int u4 = 0; u4 < UNITS / 4; ++u4) {
        const float2 ek0 = *(const float2*)(ekc + (size_t)(4 * u4 + 0) * NKROW);
        const float2 ek1 = *(const float2*)(ekc + (size_t)(4 * u4 + 1) * NKROW);
        const float2 ek2 = *(const float2*)(ekc + (size_t)(4 * u4 + 2) * NKROW);
        const float2 ek3 = *(const float2*)(ekc + (size_t)(4 * u4 + 3) * NKROW);
        const float4 s4 = *(const float4*)(s_lds + 4 * u4);
        #pragma unroll
        for (int q = 0; q < QB; ++q) {
            const float4 eq = *(const float4*)(&q_lds[q][4 * u4]);
            {   // v0: sum_{i=0..3} s_i / t_i with one rcp
                float t0 = fmaf(eq.x, ek0.x, 1.f);
                float t1 = fmaf(eq.y, ek1.x, 1.f);
                float t2 = fmaf(eq.z, ek2.x, 1.f);
                float t3 = fmaf(eq.w, ek3.x, 1.f);
                float p01 = t0 * t1, p23 = t2 * t3;
                float A  = fmaf(s4.y, t0, s4.x * t1);
                float Bq = fmaf(s4.w, t2, s4.z * t3);
                float num = fmaf(Bq, p01, A * p23);
                float r = __builtin_amdgcn_rcpf(p01 * p23);
                acc0[q] = fmaf(num, r, acc0[q]);
            }
            {   // v1
                float t0 = fmaf(eq.x, ek0.y, 1.f);
                float t1 = fmaf(eq.y, ek1.y, 1.f);
                float t2 = fmaf(eq.z, ek2.y, 1.f);
                float t3 = fmaf(eq.w, ek3.y, 1.f);
                float p01 = t0 * t1, p23 = t2 * t3;
                float A  = fmaf(s4.y, t0, s4.x * t1);
                float Bq = fmaf(s4.w, t2, s4.z * t3);
                float num = fmaf(Bq, p01, A * p23);
                float r = __builtin_amdgcn_rcpf(p01 * p23);
                acc1[q] = fmaf(num, r, acc1[q]);
            }
        }
    }

    // no-max softmax: e = exp2(-2*acc*LOG2E) directly (range-safe, see above)
    float e0[QB], e1[QB];
    #pragma unroll
    for (int q = 0; q < QB; ++q) {
        e0[q] = fast_exp2(-2.f * LOG2E * acc0[q]);
        e1[q] = fast_exp2(-2.f * LOG2E * acc1[q]);
        float s = wave_sum(e0[q] + e1[q]);
        if (lane == 0) reds[q][wid] = s;
    }
    __syncthreads();
    #pragma unroll
    for (int q = 0; q < QB; ++q) {
        float ss = reds[q][0];
        #pragma unroll
        for (int i = 1; i < SNW; ++i) ss += reds[q][i];
        const float inv = __builtin_amdgcn_rcpf(ss);
        float2 o; o.x = e0[q] * inv; o.y = e1[q] * inv;
        float* arow = out_attn + (size_t)(b * TQ + q0 + q) * TV;
        *(float2*)(arow + 2 * tid) = o;
    }
}

// ---- context partial: QC q-rows x TV/SPLIT v-range per block ----
template <int QC, int SPLIT>
__global__ __launch_bounds__(512) void ctx_kernel(
        const float* __restrict__ attn,    // [NQROW][TV]
        const float* __restrict__ value,   // [B][TV][DV]
        float* __restrict__ dst) {         // [SPLIT][NQROW][DV]
    constexpr int TVC = TV / SPLIT;
    constexpr int QT  = QC / 2;            // q rows per thread (512 thr / 256 d)
    const int tid = threadIdx.x;
    constexpr int G = (NQROW / QC) * SPLIT;
    int bid = blockIdx.x;
    bid = (bid & 7) * (G >> 3) + (bid >> 3);   // XCD swizzle (G % 8 == 0)
    const int qc = bid / SPLIT, vs = bid % SPLIT;
    const int b  = qc / (TQ / QC);
    const int q0 = (qc % (TQ / QC)) * QC;
    const int v0 = vs * TVC;
    const int d  = tid & (DV - 1);
    const int qh = __builtin_amdgcn_readfirstlane(tid >> 8) * QT;

    const float* ab = attn + (size_t)(b * TQ + q0 + qh) * TV + v0;
    const float* vb = value + ((size_t)b * TV + v0) * DV + d;

    float acc[QT] = {};
    #pragma unroll 2
    for (int v4 = 0; v4 < TVC / 4; ++v4) {
        float4 aq[QT];
        #pragma unroll
        for (int j = 0; j < QT; ++j)
            aq[j] = *(const float4*)(ab + (size_t)j * TV + v4 * 4);
        #pragma unroll
        for (int k = 0; k < 4; ++k) {
            float val = vb[(size_t)(v4 * 4 + k) * DV];
            #pragma unroll
            for (int j = 0; j < QT; ++j)
                acc[j] = fmaf(((const float*)&aq[j])[k], val, acc[j]);
        }
    }
    float* o = dst + (size_t)vs * (NQROW * DV) + (size_t)(b * TQ + q0 + qh) * DV + d;
    #pragma unroll
    for (int j = 0; j < QT; ++j)
        o[(size_t)j * DV] = acc[j];
}

// out[i] = sum over 4 partials
__global__ __launch_bounds__(256) void reduce_kernel(
        const float* __restrict__ part, float* __restrict__ out) {
    constexpr size_t S = (size_t)NQROW * DV / 4;   // float4 count per partial
    const size_t i = (size_t)blockIdx.x * 256 + threadIdx.x;
    const float4* p = (const float4*)part;
    float4 a = p[i], b4 = p[i + S], c = p[i + 2 * S], d4 = p[i + 3 * S];
    float4 r;
    r.x = (a.x + b4.x) + (c.x + d4.x);
    r.y = (a.y + b4.y) + (c.y + d4.y);
    r.z = (a.z + b4.z) + (c.z + d4.z);
    r.w = (a.w + b4.w) + (c.w + d4.w);
    ((float4*)out)[i] = r;
}

extern "C" void kernel_launch(void* const* d_in, const int* in_sizes, int n_in,
                              void* d_out, int out_size, void* d_ws, size_t ws_size,
                              hipStream_t stream) {
    const float* query = (const float*)d_in[0];
    const float* value = (const float*)d_in[1];
    const float* w1    = (const float*)d_in[2];
    const float* w2    = (const float*)d_in[3];
    const float* scale = (const float*)d_in[4];

    float* out      = (float*)d_out;
    float* out_ctx  = out;                         // [NQROW*DV]
    float* out_attn = out + (size_t)NQROW * DV;    // [NQROW*TV]

    float* Eq   = (float*)d_ws;                    // NQROW*UNITS
    float* EkT  = Eq + (size_t)NQROW * UNITS;      // UNITS*NKROW
    float* part = EkT + (size_t)UNITS * NKROW;     // 4 * NQROW*DV

    const size_t need = ((size_t)NQROW * UNITS + (size_t)UNITS * NKROW +
                         (size_t)4 * NQROW * DV) * sizeof(float);

    proj_kernel<<<dim3((NQROW + NKROW) / RPB), 256, 0, stream>>>(
        query, value, w1, w2, Eq, EkT);
    score_kernel<<<dim3(NQROW / QB), SNT, 0, stream>>>(Eq, EkT, scale, out_attn);
    if (ws_size >= need) {
        ctx_kernel<16, 4><<<dim3((NQROW / 16) * 4), 512, 0, stream>>>(out_attn, value, part);
        reduce_kernel<<<dim3(NQROW * DV / 4 / 256), 256, 0, stream>>>(part, out_ctx);
    } else {
        ctx_kernel<8, 1><<<dim3(NQROW / 8), 512, 0, stream>>>(out_attn, value, out_ctx);
    }
}

// Round 10
// 57.948 us; speedup vs baseline: 1.4106x; 1.0279x over previous
//
#include <hip/hip_runtime.h>
#include <math.h>

#define B 4
#define TQ 512
#define TV 1024
#define DQ 256
#define DV 256
#define UNITS 64
#define NQROW (B * TQ)   // 2048
#define NKROW (B * TV)   // 4096

#define CEXP  2.885390081777927f    // 2*log2(e): exp(2x) == exp2(CEXP*x)
#define LOG2E 1.4426950408889634f

__device__ __forceinline__ float fast_exp2(float x) {
#if __has_builtin(__builtin_amdgcn_exp2f)
    return __builtin_amdgcn_exp2f(x);
#else
    return __expf(0.6931471805599453f * x);
#endif
}

__device__ __forceinline__ float wave_sum(float v) {
    #pragma unroll
    for (int off = 32; off > 0; off >>= 1)
        v += __shfl_xor(v, off, 64);
    return v;
}

// ---- projections: d-split. 8 rows/block staged in LDS; each of 4 waves
// handles a 64-wide d-range for ALL rows -> one pass over w per block
// (49 MB total w traffic vs 196 MB for row-split). Partials reduced in LDS.
#define RPB 8
__global__ __launch_bounds__(256) void proj_kernel(
        const float* __restrict__ query, const float* __restrict__ value,
        const float* __restrict__ w1, const float* __restrict__ w2,
        float* __restrict__ Eq, float* __restrict__ EkT) {
    __shared__ float rows[RPB][DQ];            // 8 KB
    __shared__ float part[4][RPB][UNITS + 2];  // padded vs bank conflicts
    const int tid = threadIdx.x;
    const int u   = tid & 63;
    const int wid = tid >> 6;                  // 0..3 -> d-range
    const int row0 = blockIdx.x * RPB;
    const bool isq = row0 < NQROW;
    const float* in = isq ? query + (size_t)row0 * DQ
                          : value + (size_t)(row0 - NQROW) * DQ;
    const float* w  = isq ? w1 : w2;

    // stage 8 rows (2048 floats) coalesced
    {
        const float4* src = (const float4*)in;
        float4* dst = (float4*)&rows[0][0];
        dst[tid]       = src[tid];
        dst[tid + 256] = src[tid + 256];
    }
    __syncthreads();

    // wave wid covers c in [wid*16, wid*16+16)  (d = 4c..4c+3)
    float a[RPB] = {};
    const int c0 = wid * 16;
    #pragma unroll 4
    for (int ci = 0; ci < 16; ++ci) {
        const int c = c0 + ci;
        const float w0v = w[(4 * c + 0) * UNITS + u];
        const float w1v = w[(4 * c + 1) * UNITS + u];
        const float w2v = w[(4 * c + 2) * UNITS + u];
        const float w3v = w[(4 * c + 3) * UNITS + u];
        #pragma unroll
        for (int r = 0; r < RPB; ++r) {
            const float4 t = *(const float4*)&rows[r][4 * c];
            a[r] = fmaf(t.x, w0v, a[r]);
            a[r] = fmaf(t.y, w1v, a[r]);
            a[r] = fmaf(t.z, w2v, a[r]);
            a[r] = fmaf(t.w, w3v, a[r]);
        }
    }
    #pragma unroll
    for (int r = 0; r < RPB; ++r)
        part[wid][r][u] = a[r];
    __syncthreads();

    if (isq) {
        #pragma unroll
        for (int h = 0; h < 2; ++h) {
            const int p = tid + h * 256;
            const int row = p >> 6, uu = p & 63;
            const float s = (part[0][row][uu] + part[1][row][uu]) +
                            (part[2][row][uu] + part[3][row][uu]);
            Eq[(size_t)(row0 + row) * UNITS + uu] = fast_exp2(CEXP * s);
        }
    } else {
        #pragma unroll
        for (int h = 0; h < 2; ++h) {
            const int p = tid + h * 256;
            const int uu = p >> 3, r = p & 7;
            const float s = (part[0][r][uu] + part[1][r][uu]) +
                            (part[2][r][uu] + part[3][r][uu]);
            EkT[(size_t)uu * NKROW + (row0 - NQROW) + r] = fast_exp2(CEXP * s);
        }
    }
}

// ---- scores + softmax: u-quad rcp fusion + no-max softmax (round-9) ----
#define QB 4
#define SNT 512
#define SNW (SNT / 64)
// grid = NQROW/QB = 512 blocks, 512 threads; thread owns v = {2*tid, 2*tid+1}
__global__ __launch_bounds__(SNT) void score_kernel(
        const float* __restrict__ Eq,      // [NQROW][UNITS]
        const float* __restrict__ EkT,     // [UNITS][NKROW]
        const float* __restrict__ scale,   // [UNITS]
        float* __restrict__ out_attn) {    // [NQROW][TV]
    __shared__ float q_lds[QB][UNITS];
    __shared__ float s_lds[UNITS];
    __shared__ float reds[QB][SNW];

    const int tid = threadIdx.x, lane = tid & 63, wid = tid >> 6;
    int bid = blockIdx.x;
    bid = (bid & 7) * ((NQROW / QB) >> 3) + (bid >> 3);   // XCD swizzle, bijective
    const int b  = bid / (TQ / QB);
    const int q0 = (bid % (TQ / QB)) * QB;

    if (tid < QB * UNITS)
        q_lds[tid >> 6][tid & 63] =
            Eq[(size_t)(b * TQ + q0 + (tid >> 6)) * UNITS + (tid & 63)];
    else if (tid < QB * UNITS + UNITS)
        s_lds[tid - QB * UNITS] = scale[tid - QB * UNITS];
    __syncthreads();

    const float* ekc = EkT + (size_t)b * TV + 2 * tid;
    float acc0[QB] = {}, acc1[QB] = {};

    #pragma unroll 4
    for (int u4 = 0; u4 < UNITS / 4; ++u4) {
        const float2 ek0 = *(const float2*)(ekc + (size_t)(4 * u4 + 0) * NKROW);
        const float2 ek1 = *(const float2*)(ekc + (size_t)(4 * u4 + 1) * NKROW);
        const float2 ek2 = *(const float2*)(ekc + (size_t)(4 * u4 + 2) * NKROW);
        const float2 ek3 = *(const float2*)(ekc + (size_t)(4 * u4 + 3) * NKROW);
        const float4 s4 = *(const float4*)(s_lds + 4 * u4);
        #pragma unroll
        for (int q = 0; q < QB; ++q) {
            const float4 eq = *(const float4*)(&q_lds[q][4 * u4]);
            {   // v0: sum_{i=0..3} s_i / t_i with one rcp
                float t0 = fmaf(eq.x, ek0.x, 1.f);
                float t1 = fmaf(eq.y, ek1.x, 1.f);
                float t2 = fmaf(eq.z, ek2.x, 1.f);
                float t3 = fmaf(eq.w, ek3.x, 1.f);
                float p01 = t0 * t1, p23 = t2 * t3;
                float A  = fmaf(s4.y, t0, s4.x * t1);
                float Bq = fmaf(s4.w, t2, s4.z * t3);
                float num = fmaf(Bq, p01, A * p23);
                float r = __builtin_amdgcn_rcpf(p01 * p23);
                acc0[q] = fmaf(num, r, acc0[q]);
            }
            {   // v1
                float t0 = fmaf(eq.x, ek0.y, 1.f);
                float t1 = fmaf(eq.y, ek1.y, 1.f);
                float t2 = fmaf(eq.z, ek2.y, 1.f);
                float t3 = fmaf(eq.w, ek3.y, 1.f);
                float p01 = t0 * t1, p23 = t2 * t3;
                float A  = fmaf(s4.y, t0, s4.x * t1);
                float Bq = fmaf(s4.w, t2, s4.z * t3);
                float num = fmaf(Bq, p01, A * p23);
                float r = __builtin_amdgcn_rcpf(p01 * p23);
                acc1[q] = fmaf(num, r, acc1[q]);
            }
        }
    }

    // no-max softmax: e = exp2(-2*acc*LOG2E) directly (range-safe)
    float e0[QB], e1[QB];
    #pragma unroll
    for (int q = 0; q < QB; ++q) {
        e0[q] = fast_exp2(-2.f * LOG2E * acc0[q]);
        e1[q] = fast_exp2(-2.f * LOG2E * acc1[q]);
        float s = wave_sum(e0[q] + e1[q]);
        if (lane == 0) reds[q][wid] = s;
    }
    __syncthreads();
    #pragma unroll
    for (int q = 0; q < QB; ++q) {
        float ss = reds[q][0];
        #pragma unroll
        for (int i = 1; i < SNW; ++i) ss += reds[q][i];
        const float inv = __builtin_amdgcn_rcpf(ss);
        float2 o; o.x = e0[q] * inv; o.y = e1[q] * inv;
        float* arow = out_attn + (size_t)(b * TQ + q0 + q) * TV;
        *(float2*)(arow + 2 * tid) = o;
    }
}

// ---- context partial: QC q-rows x TV/SPLIT v-range per block ----
template <int QC, int SPLIT>
__global__ __launch_bounds__(512) void ctx_kernel(
        const float* __restrict__ attn,    // [NQROW][TV]
        const float* __restrict__ value,   // [B][TV][DV]
        float* __restrict__ dst) {         // [SPLIT][NQROW][DV]
    constexpr int TVC = TV / SPLIT;
    constexpr int QT  = QC / 2;            // q rows per thread (512 thr / 256 d)
    const int tid = threadIdx.x;
    constexpr int G = (NQROW / QC) * SPLIT;
    int bid = blockIdx.x;
    bid = (bid & 7) * (G >> 3) + (bid >> 3);   // XCD swizzle (G % 8 == 0)
    const int qc = bid / SPLIT, vs = bid % SPLIT;
    const int b  = qc / (TQ / QC);
    const int q0 = (qc % (TQ / QC)) * QC;
    const int v0 = vs * TVC;
    const int d  = tid & (DV - 1);
    const int qh = __builtin_amdgcn_readfirstlane(tid >> 8) * QT;

    const float* ab = attn + (size_t)(b * TQ + q0 + qh) * TV + v0;
    const float* vb = value + ((size_t)b * TV + v0) * DV + d;

    float acc[QT] = {};
    #pragma unroll 2
    for (int v4 = 0; v4 < TVC / 4; ++v4) {
        float4 aq[QT];
        #pragma unroll
        for (int j = 0; j < QT; ++j)
            aq[j] = *(const float4*)(ab + (size_t)j * TV + v4 * 4);
        #pragma unroll
        for (int k = 0; k < 4; ++k) {
            float val = vb[(size_t)(v4 * 4 + k) * DV];
            #pragma unroll
            for (int j = 0; j < QT; ++j)
                acc[j] = fmaf(((const float*)&aq[j])[k], val, acc[j]);
        }
    }
    float* o = dst + (size_t)vs * (NQROW * DV) + (size_t)(b * TQ + q0 + qh) * DV + d;
    #pragma unroll
    for (int j = 0; j < QT; ++j)
        o[(size_t)j * DV] = acc[j];
}

// out[i] = sum over 4 partials
__global__ __launch_bounds__(256) void reduce_kernel(
        const float* __restrict__ part, float* __restrict__ out) {
    constexpr size_t S = (size_t)NQROW * DV / 4;   // float4 count per partial
    const size_t i = (size_t)blockIdx.x * 256 + threadIdx.x;
    const float4* p = (const float4*)part;
    float4 a = p[i], b4 = p[i + S], c = p[i + 2 * S], d4 = p[i + 3 * S];
    float4 r;
    r.x = (a.x + b4.x) + (c.x + d4.x);
    r.y = (a.y + b4.y) + (c.y + d4.y);
    r.z = (a.z + b4.z) + (c.z + d4.z);
    r.w = (a.w + b4.w) + (c.w + d4.w);
    ((float4*)out)[i] = r;
}

extern "C" void kernel_launch(void* const* d_in, const int* in_sizes, int n_in,
                              void* d_out, int out_size, void* d_ws, size_t ws_size,
                              hipStream_t stream) {
    const float* query = (const float*)d_in[0];
    const float* value = (const float*)d_in[1];
    const float* w1    = (const float*)d_in[2];
    const float* w2    = (const float*)d_in[3];
    const float* scale = (const float*)d_in[4];

    float* out      = (float*)d_out;
    float* out_ctx  = out;                         // [NQROW*DV]
    float* out_attn = out + (size_t)NQROW * DV;    // [NQROW*TV]

    float* Eq   = (float*)d_ws;                    // NQROW*UNITS
    float* EkT  = Eq + (size_t)NQROW * UNITS;      // UNITS*NKROW
    float* part = EkT + (size_t)UNITS * NKROW;     // 4 * NQROW*DV

    const size_t need = ((size_t)NQROW * UNITS + (size_t)UNITS * NKROW +
                         (size_t)4 * NQROW * DV) * sizeof(float);

    proj_kernel<<<dim3((NQROW + NKROW) / RPB), 256, 0, stream>>>(
        query, value, w1, w2, Eq, EkT);
    score_kernel<<<dim3(NQROW / QB), SNT, 0, stream>>>(Eq, EkT, scale, out_attn);
    if (ws_size >= need) {
        ctx_kernel<16, 4><<<dim3((NQROW / 16) * 4), 512, 0, stream>>>(out_attn, value, part);
        reduce_kernel<<<dim3(NQROW * DV / 4 / 256), 256, 0, stream>>>(part, out_ctx);
    } else {
        ctx_kernel<8, 1><<<dim3(NQROW / 8), 512, 0, stream>>>(out_attn, value, out_ctx);
    }
}